// Round 4
// baseline (183.471 us; speedup 1.0000x reference)
//
#include <hip/hip_runtime.h>

#define BSZ 8
#define PN  2048
#define CIN 512
#define CAP 2048
#define NW  16

// ws layout (bytes):
//   accum @ 0       : f[0..3]=S, f[4..7]=imb, [8]=ticket, [9]=grid barrier
//   meta  @ 64      : 24 ints (padded list length per (b,c))
//   sList @ 1024    : 24*2048 floats   (score, list order)
//   roiL  @ 394240  : 24*2048 float4   (roi, list order)
//   pbn   @ 1180672 : 24*2*2048 floats (partial best numerator)
//   pbd   @ 1573888 : 24*2*2048 floats (partial best denominator)
//   pbp   @ 1967104 : 24*2*2048 ints   (partial best list position)

// ---------------- K1: sel (blocks 0..23) | fc all rows (24..1047) -----------
__global__ __launch_bounds__(256) void k_front(
    const float* __restrict__ inp, const float* __restrict__ fcw,
    const float* __restrict__ fcb, const float* __restrict__ ps,
    const float* __restrict__ labels, const float* __restrict__ rois,
    float* __restrict__ logit, float* __restrict__ accum,
    int* __restrict__ meta, float* __restrict__ sList,
    float4* __restrict__ roiList)
{
  const int t = threadIdx.x;
  if (blockIdx.x >= 24) {
    // ---- fc + softmax: wave-per-row-quad (proven round-0 code) ----
    const int gw   = (((int)blockIdx.x - 24) * 256 + t) >> 6;  // 0..4095
    const int lane = t & 63;
    const int kb   = lane << 2;
    const float4 wa0 = *(const float4*)(fcw + (kb + 0) * 4);
    const float4 wa1 = *(const float4*)(fcw + (kb + 1) * 4);
    const float4 wa2 = *(const float4*)(fcw + (kb + 2) * 4);
    const float4 wa3 = *(const float4*)(fcw + (kb + 3) * 4);
    const float4 wb0 = *(const float4*)(fcw + (256 + kb + 0) * 4);
    const float4 wb1 = *(const float4*)(fcw + (256 + kb + 1) * 4);
    const float4 wb2 = *(const float4*)(fcw + (256 + kb + 2) * 4);
    const float4 wb3 = *(const float4*)(fcw + (256 + kb + 3) * 4);
    const float4 bias = *(const float4*)fcb;
    #pragma unroll
    for (int rr = 0; rr < 4; ++rr) {
      const int r = (gw << 2) + rr;                 // row 0..16383
      const float* row = inp + r * CIN;
      const float4 xa = *(const float4*)(row + kb);
      const float4 xb = *(const float4*)(row + 256 + kb);
      float a0 = xa.x*wa0.x + xa.y*wa1.x + xa.z*wa2.x + xa.w*wa3.x
               + xb.x*wb0.x + xb.y*wb1.x + xb.z*wb2.x + xb.w*wb3.x;
      float a1 = xa.x*wa0.y + xa.y*wa1.y + xa.z*wa2.y + xa.w*wa3.y
               + xb.x*wb0.y + xb.y*wb1.y + xb.z*wb2.y + xb.w*wb3.y;
      float a2 = xa.x*wa0.z + xa.y*wa1.z + xa.z*wa2.z + xa.w*wa3.z
               + xb.x*wb0.z + xb.y*wb1.z + xb.z*wb2.z + xb.w*wb3.z;
      float a3 = xa.x*wa0.w + xa.y*wa1.w + xa.z*wa2.w + xa.w*wa3.w
               + xb.x*wb0.w + xb.y*wb1.w + xb.z*wb2.w + xb.w*wb3.w;
      #pragma unroll
      for (int off = 32; off; off >>= 1) {
        a0 += __shfl_xor(a0, off); a1 += __shfl_xor(a1, off);
        a2 += __shfl_xor(a2, off); a3 += __shfl_xor(a3, off);
      }
      if (lane == 0) {
        a0 += bias.x; a1 += bias.y; a2 += bias.z; a3 += bias.w;
        const float m  = fmaxf(fmaxf(a0, a1), fmaxf(a2, a3));
        const float e0 = expf(a0 - m), e1 = expf(a1 - m);
        const float e2 = expf(a2 - m), e3 = expf(a3 - m);
        const float inv = 1.0f / (e0 + e1 + e2 + e3);
        float4 o; o.x = e0*inv; o.y = e1*inv; o.z = e2*inv; o.w = e3*inv;
        *(float4*)(logit + r * 4) = o;
      }
    }
    return;
  }

  // ---- selection -> compacted per-(b,c) roi+score lists (proven code) ----
  const int bc = blockIdx.x;                        // 0..23
  if (bc == 0 && t < 16) accum[t] = 0.0f;           // zero sums+ticket+barrier
  const int b = bc / 3;
  const int c = bc % 3;
  const int j0 = t * 8;

  float sv[8];
  int   flg = 0, cnt = 0;
  float vmax = -1e30f;
  int   jmax = 0;
  #pragma unroll
  for (int m = 0; m < 8; ++m) {
    const float s = ps[(b * PN + j0 + m) * 4 + c];
    sv[m] = s;
    if (s > 0.5f) { flg |= 1 << m; ++cnt; }
    if (s > vmax) { vmax = s; jmax = j0 + m; }      // ascending: > = first
  }

  __shared__ float lv[256];
  __shared__ int   lj[256];
  __shared__ int   pre[256];
  lv[t] = vmax; lj[t] = jmax; pre[t] = cnt;
  __syncthreads();
  for (int off = 128; off > 0; off >>= 1) {         // argmax reduce
    if (t < off) {
      const float v2 = lv[t + off]; const int j2 = lj[t + off];
      if (v2 > lv[t] || (v2 == lv[t] && j2 < lj[t])) { lv[t] = v2; lj[t] = j2; }
    }
    __syncthreads();
  }
  for (int off = 1; off < 256; off <<= 1) {         // inclusive scan
    const int add = (t >= off) ? pre[t - off] : 0;
    __syncthreads();
    pre[t] += add;
    __syncthreads();
  }
  const int  totalTh = pre[255];
  const int  excl    = pre[t] - cnt;
  const int  jArg    = lj[0];
  const bool lab     = labels[b * 4 + c] != 0.0f;
  const int  L    = (!lab) ? 0 : ((totalTh > 1) ? totalTh : 1);
  const int  Lpad = (L + 7) & ~7;

  __shared__ float4 lastRoi;
  __shared__ float  lastS;
  float4* dstR = roiList + bc * CAP;
  float*  dstS = sList   + bc * CAP;
  const float4* rb = ((const float4*)rois) + b * PN;

  if (lab) {
    if (totalTh > 1) {
      int pos = excl;
      #pragma unroll
      for (int m = 0; m < 8; ++m) {
        if (flg & (1 << m)) {
          const float4 r = rb[j0 + m];
          dstR[pos] = r; dstS[pos] = sv[m];
          if (pos == L - 1) { lastRoi = r; lastS = sv[m]; }
          ++pos;
        }
      }
    } else if (t == (jArg >> 3)) {
      const float4 r = rb[jArg];
      dstR[0] = r; dstS[0] = sv[jArg & 7];
      lastRoi = r; lastS = sv[jArg & 7];
    }
  }
  __syncthreads();
  if (t < Lpad - L) { dstR[L + t] = lastRoi; dstS[L + t] = lastS; }
  if (t == 0) meta[bc] = Lpad;
}

// ---------------- K2: IoU (all 16 waves) + grid barrier + epilogue ----------
// block = (b, h, itile128). 16 waves split the j-list 16-way; 2 i per lane;
// area recomputed in-loop. After pb* writes, device-scope arrive; blocks
// 0..15 spin (barrier word zeroed by K1 -- safe vs ws poison), then run the
// loss epilogue on L2-warm pb*. 256 blocks <= 1/CU -> co-resident; only 16
// blocks spin -> no deadlock possible.
__global__ __launch_bounds__(1024, 4) void k_mid(
    const float* __restrict__ rois, const int* __restrict__ meta,
    const float4* __restrict__ roiList, const float* __restrict__ sList,
    const float* __restrict__ logit, const float* __restrict__ labels,
    float* __restrict__ accum, float* __restrict__ loss,
    float* __restrict__ pbn, float* __restrict__ pbd, int* __restrict__ pbp)
{
  const int blk  = blockIdx.x;                      // 0..255
  const int t    = threadIdx.x;
  const int lane = t & 63;
  const int wv   = t >> 6;

  const int b  = blk >> 5;
  const int h  = (blk >> 4) & 1;
  const int it = blk & 15;

  __shared__ __align__(16) float4 sroi[3 * 1024];   // 48 KB
  float* mn = (float*)sroi;                         // merge aliases (post-B2)
  float* md = (float*)sroi + 3072;                  // 3*16*64 floats each
  int*   mp = (int*)((float*)sroi + 6144);

  int startc[3], cntc[3];
  #pragma unroll
  for (int c = 0; c < 3; ++c) {
    const int L  = meta[b * 3 + c];                 // padded, mult of 8
    const int L2 = ((L >> 1) + 7) & ~7;             // h-split point
    const int s0 = h ? L2 : 0;
    const int e0 = h ? L  : L2;
    startc[c] = s0;
    cntc[c]   = e0 - s0;                            // <= 1024, mult of 8
    if (t < cntc[c])                                // one coalesced step
      sroi[c * 1024 + t] = roiList[(b * 3 + c) * CAP + s0 + t];
  }
  const int i0 = (it << 7) + lane;                  // i0 and i0+64
  const float4 ri0 = ((const float4*)rois)[b * PN + i0];
  const float4 ri1 = ((const float4*)rois)[b * PN + i0 + 64];
  const float ar0 = (ri0.z - ri0.x) * (ri0.w - ri0.y);
  const float ar1 = (ri1.z - ri1.x) * (ri1.w - ri1.y);
  __syncthreads();                                  // B1: lists staged

  auto upd = [](const float4 ri, const float ai,
                float& n, float& d, int& p,
                const float4 rj, const float aj, const int pos) {
    const float lx = fmaxf(ri.x, rj.x), ly = fmaxf(ri.y, rj.y);
    const float rx = fminf(ri.z, rj.z), ry = fminf(ri.w, rj.w);
    const float ww = fmaxf(rx - lx, 0.0f), hh = fmaxf(ry - ly, 0.0f);
    const float inter = ww * hh;
    const float uni   = ai + aj - inter;            // >= 1 always
    if (inter * d > n * uni) { n = inter; d = uni; p = pos; }
  };

  float BN[3][2], BD[3][2]; int BP[3][2];
  #pragma unroll
  for (int c = 0; c < 3; ++c) {
    const int cnt = cntc[c];
    const int C   = (((cnt + 15) >> 4) + 7) & ~7;   // per-wave chunk, mult 8
    const int g0  = wv * C;
    int g1 = g0 + C; if (g1 > cnt) g1 = cnt;
    const float4* rbase = sroi + c * 1024;
    // 4 independent chains: (i0,even) (i1,even) (i0,odd) (i1,odd)
    float n0A = -2.0f, d0A = 1.0f, n0B = -2.0f, d0B = 1.0f;
    float n1A = -2.0f, d1A = 1.0f, n1B = -2.0f, d1B = 1.0f;
    int   p0A = 0, p0B = 0, p1A = 0, p1B = 0;

    for (int g = g0; g < g1; g += 2) {              // cnt mult of 8 -> exact
      const float4 r0_ = rbase[g], r1_ = rbase[g + 1];
      const float  a0_ = (r0_.z - r0_.x) * (r0_.w - r0_.y);  // recompute:
      const float  a1_ = (r1_.z - r1_.x) * (r1_.w - r1_.y);  // == sel's expr
      upd(ri0, ar0, n0A, d0A, p0A, r0_, a0_, g);    // each j feeds 2 chains
      upd(ri1, ar1, n1A, d1A, p1A, r0_, a0_, g);
      upd(ri0, ar0, n0B, d0B, p0B, r1_, a1_, g + 1);
      upd(ri1, ar1, n1B, d1B, p1B, r1_, a1_, g + 1);
    }
    // merge B into A; exact tie -> lower position (ref = first max)
    {
      const float tB = n0B * d0A, tA = n0A * d0B;
      if (tB > tA || (tB == tA && p0B < p0A)) { n0A = n0B; d0A = d0B; p0A = p0B; }
    }
    {
      const float tB = n1B * d1A, tA = n1A * d1B;
      if (tB > tA || (tB == tA && p1B < p1A)) { n1A = n1B; d1A = d1B; p1A = p1B; }
    }
    BN[c][0] = n0A; BD[c][0] = d0A; BP[c][0] = p0A + startc[c];
    BN[c][1] = n1A; BD[c][1] = d1A; BP[c][1] = p1A + startc[c];
  }
  __syncthreads();                                  // B2: sroi reads done
  #pragma unroll
  for (int ii = 0; ii < 2; ++ii) {                  // two-pass 16-way merge
    #pragma unroll
    for (int c = 0; c < 3; ++c) {
      mn[(c * NW + wv) * 64 + lane] = BN[c][ii];
      md[(c * NW + wv) * 64 + lane] = BD[c][ii];
      mp[(c * NW + wv) * 64 + lane] = BP[c][ii];
    }
    __syncthreads();
    if (wv == 0) {
      #pragma unroll
      for (int c = 0; c < 3; ++c) {
        float bn = BN[c][ii], bd = BD[c][ii]; int bp = BP[c][ii];
        for (int w2 = 1; w2 < NW; ++w2) {           // wv-ascending: > = first
          const float n = mn[(c * NW + w2) * 64 + lane];
          const float d = md[(c * NW + w2) * 64 + lane];
          const int   p = mp[(c * NW + w2) * 64 + lane];
          if (n * bd > bn * d) { bn = n; bd = d; bp = p; }
        }
        const int ig = (it << 7) + (ii << 6) + lane;
        const int o  = ((b * 3 + c) * 2 + h) * PN + ig;
        pbn[o] = bn; pbd[o] = bd; pbp[o] = bp;
      }
    }
    __syncthreads();                                // protect ii=1 overwrite
  }

  // ---- device-scope grid barrier (word zeroed by K1) ----
  __threadfence();                                  // flush pb* (all threads)
  __syncthreads();
  if (t == 0)
    __hip_atomic_fetch_add((int*)(accum + 9), 1,
                           __ATOMIC_ACQ_REL, __HIP_MEMORY_SCOPE_AGENT);
  if (blk >= 16) return;                            // non-epilogue blocks done

  if (t == 0) {
    while (__hip_atomic_load((int*)(accum + 9),
                             __ATOMIC_ACQUIRE, __HIP_MEMORY_SCOPE_AGENT) < 256)
      __builtin_amdgcn_s_sleep(1);
  }
  __syncthreads();
  __threadfence();                                  // see remote pb* writes

  // ---- epilogue: 16 blocks x 1024 threads cover gi 0..16383 ----
  const int gi = (blk << 10) + t;
  const int eb = gi >> 11;
  const int ei = gi & (PN - 1);

  float v[3], sc[3];
  #pragma unroll
  for (int c = 0; c < 3; ++c) {
    const int o0 = ((eb * 3 + c) * 2) * PN + ei;
    float n = pbn[o0], d = pbd[o0]; int p = pbp[o0];
    const float n1 = pbn[o0 + PN], d1 = pbd[o0 + PN];
    const int   p1 = pbp[o0 + PN];
    if (n1 * d > n * d1) { n = n1; d = d1; p = p1; }  // h-ascending: > = first
    v[c]  = n / d;                                    // exact IEEE divide
    sc[c] = sList[(eb * 3 + c) * CAP + p];
  }
  float runI = -1.0f, runw = 1.0f;
  if (v[0] > runI) { runw = sc[0]; runI = v[0]; }
  if (v[1] > runI) { runw = sc[1]; runI = v[1]; }
  if (v[2] > runI) { runw = sc[2]; runI = v[2]; }
  const float y0 = (v[0] > 0.5f) ? 1.0f : 0.0f;
  const float y1 = (v[1] > 0.5f) ? 1.0f : 0.0f;
  const float y2 = (v[2] > 0.5f) ? 1.0f : 0.0f;
  const float y3 = (y0 + y1 + y2 == 0.0f) ? 1.0f : 0.0f;

  const float4 lg = ((const float4*)logit)[gi];
  const float lb0 = labels[eb * 4 + 0];
  const float lb1 = labels[eb * 4 + 1];
  const float lb2 = labels[eb * 4 + 2];

  auto term = [&](const float l, const float yv, const float labv) -> float {
    const float p  = fminf(fmaxf(l, 1e-7f), 1.0f - 1e-7f);
    const float om = 1.0f - p;
    const float fl = -yv * logf(p) * om * om;       // focal, gamma=2
    const float wl = 10.0f * expf(l) * (1.0f - labv) + labv;
    return runw * fl * wl;                          // /imb deferred
  };
  float s[8];
  s[0] = term(lg.x, y0, lb0); s[1] = term(lg.y, y1, lb1);
  s[2] = term(lg.z, y2, lb2); s[3] = term(lg.w, y3, 1.0f);
  s[4] = y0; s[5] = y1; s[6] = y2; s[7] = y3;

  #pragma unroll
  for (int k = 0; k < 8; ++k)
    #pragma unroll
    for (int off = 32; off; off >>= 1) s[k] += __shfl_xor(s[k], off);

  __shared__ float red[NW][8];
  if (lane == 0)
    #pragma unroll
    for (int k = 0; k < 8; ++k) red[wv][k] = s[k];
  __syncthreads();
  if (t < 8) {
    float sum = 0.0f;
    #pragma unroll
    for (int w2 = 0; w2 < NW; ++w2) sum += red[w2][t];
    atomicAdd(&accum[t], sum);
  }
  __syncthreads();                                  // block's 8 adds drained
  if (t == 0) {
    __threadfence();
    const int ticket = __hip_atomic_fetch_add((int*)(accum + 8), 1,
                        __ATOMIC_ACQ_REL, __HIP_MEMORY_SCOPE_AGENT);
    if (ticket == 15) {                             // last block finalizes
      float L = 0.0f;
      #pragma unroll
      for (int c = 0; c < 4; ++c) {
        const float num = __hip_atomic_load(accum + c,
                            __ATOMIC_RELAXED, __HIP_MEMORY_SCOPE_AGENT);
        const float den = __hip_atomic_load(accum + 4 + c,
                            __ATOMIC_RELAXED, __HIP_MEMORY_SCOPE_AGENT);
        L += num / (den + 1e-7f);
      }
      loss[0] = L * 0.125f;                         // / bs, exact (pow2)
    }
  }
}

extern "C" void kernel_launch(void* const* d_in, const int* in_sizes, int n_in,
                              void* d_out, int out_size, void* d_ws, size_t ws_size,
                              hipStream_t stream)
{
  (void)in_sizes; (void)n_in; (void)out_size; (void)ws_size;
  const float* inp    = (const float*)d_in[0];
  const float* fcw    = (const float*)d_in[1];
  const float* fcb    = (const float*)d_in[2];
  const float* ps     = (const float*)d_in[3];
  const float* labels = (const float*)d_in[4];
  const float* rois   = (const float*)d_in[5];
  float* out = (float*)d_out;                       // 65536 logit + 1 loss

  char* ws = (char*)d_ws;
  float*  accum   = (float*) (ws);
  int*    meta    = (int*)   (ws + 64);
  float*  sList   = (float*) (ws + 1024);
  float4* roiL    = (float4*)(ws + 394240);
  float*  pbn     = (float*) (ws + 1180672);
  float*  pbd     = (float*) (ws + 1573888);
  int*    pbp     = (int*)   (ws + 1967104);

  k_front<<<1048, 256,  0, stream>>>(inp, fcw, fcb, ps, labels, rois,
                                     out, accum, meta, sList, roiL);
  k_mid  <<<256,  1024, 0, stream>>>(rois, meta, roiL, sList, out, labels,
                                     accum, out + BSZ * PN * 4, pbn, pbd, pbp);
}

// Round 5
// 116.462 us; speedup vs baseline: 1.5754x; 1.5754x over previous
//
#include <hip/hip_runtime.h>

#define BSZ 8
#define PN  2048
#define CIN 512
#define CAP 2048
#define NW  16

// ws layout (bytes):
//   accum @ 0       : 8 floats (S[4], imb[4]) + int ticket @ accum[8]
//   meta  @ 64      : 24 ints (padded list length per (b,c))
//   sList @ 1024    : 24*2048 floats   (score, list order)
//   areaL @ 197632  : 24*2048 floats   (precomputed area)
//   roiL  @ 394240  : 24*2048 float4   (roi, list order)
//   pbn   @ 1180672 : 24*2*2048 floats (partial best numerator)
//   pbd   @ 1573888 : 24*2*2048 floats (partial best denominator)
//   pbp   @ 1967104 : 24*2*2048 ints   (partial best list position)

// ---------------- K1: fc+softmax (blocks 24..1047) | select (0..23) ---------
__global__ __launch_bounds__(256) void k_front(
    const float* __restrict__ inp, const float* __restrict__ fcw,
    const float* __restrict__ fcb, const float* __restrict__ ps,
    const float* __restrict__ labels, const float* __restrict__ rois,
    float* __restrict__ logit, float* __restrict__ accum,
    int* __restrict__ meta, float* __restrict__ sList,
    float* __restrict__ areaL, float4* __restrict__ roiList)
{
  const int t = threadIdx.x;
  if (blockIdx.x >= 24) {
    // ---- fc + softmax: wave-per-row-quad, shuffle reduce (round-0 code) ----
    const int gw   = (((int)blockIdx.x - 24) * 256 + t) >> 6;  // 0..4095
    const int lane = t & 63;
    const int kb   = lane << 2;
    const float4 wa0 = *(const float4*)(fcw + (kb + 0) * 4);
    const float4 wa1 = *(const float4*)(fcw + (kb + 1) * 4);
    const float4 wa2 = *(const float4*)(fcw + (kb + 2) * 4);
    const float4 wa3 = *(const float4*)(fcw + (kb + 3) * 4);
    const float4 wb0 = *(const float4*)(fcw + (256 + kb + 0) * 4);
    const float4 wb1 = *(const float4*)(fcw + (256 + kb + 1) * 4);
    const float4 wb2 = *(const float4*)(fcw + (256 + kb + 2) * 4);
    const float4 wb3 = *(const float4*)(fcw + (256 + kb + 3) * 4);
    const float4 bias = *(const float4*)fcb;
    #pragma unroll
    for (int rr = 0; rr < 4; ++rr) {
      const int r = (gw << 2) + rr;                 // row 0..16383
      const float* row = inp + r * CIN;
      const float4 xa = *(const float4*)(row + kb);
      const float4 xb = *(const float4*)(row + 256 + kb);
      float a0 = xa.x*wa0.x + xa.y*wa1.x + xa.z*wa2.x + xa.w*wa3.x
               + xb.x*wb0.x + xb.y*wb1.x + xb.z*wb2.x + xb.w*wb3.x;
      float a1 = xa.x*wa0.y + xa.y*wa1.y + xa.z*wa2.y + xa.w*wa3.y
               + xb.x*wb0.y + xb.y*wb1.y + xb.z*wb2.y + xb.w*wb3.y;
      float a2 = xa.x*wa0.z + xa.y*wa1.z + xa.z*wa2.z + xa.w*wa3.z
               + xb.x*wb0.z + xb.y*wb1.z + xb.z*wb2.z + xb.w*wb3.z;
      float a3 = xa.x*wa0.w + xa.y*wa1.w + xa.z*wa2.w + xa.w*wa3.w
               + xb.x*wb0.w + xb.y*wb1.w + xb.z*wb2.w + xb.w*wb3.w;
      #pragma unroll
      for (int off = 32; off; off >>= 1) {
        a0 += __shfl_xor(a0, off); a1 += __shfl_xor(a1, off);
        a2 += __shfl_xor(a2, off); a3 += __shfl_xor(a3, off);
      }
      if (lane == 0) {
        a0 += bias.x; a1 += bias.y; a2 += bias.z; a3 += bias.w;
        const float m  = fmaxf(fmaxf(a0, a1), fmaxf(a2, a3));
        const float e0 = expf(a0 - m), e1 = expf(a1 - m);
        const float e2 = expf(a2 - m), e3 = expf(a3 - m);
        const float inv = 1.0f / (e0 + e1 + e2 + e3);
        float4 o; o.x = e0*inv; o.y = e1*inv; o.z = e2*inv; o.w = e3*inv;
        *(float4*)(logit + r * 4) = o;
      }
    }
    return;
  }

  // ---- selection -> compacted per-(b,c) lists (roi, area, score) ----
  const int bc = blockIdx.x;                        // 0..23
  if (bc == 0 && t < 12) accum[t] = 0.0f;           // zero sums + ticket
  const int b = bc / 3;
  const int c = bc % 3;
  const int j0 = t * 8;

  float sv[8];
  int   flg = 0, cnt = 0;
  float vmax = -1e30f;
  int   jmax = 0;
  #pragma unroll
  for (int m = 0; m < 8; ++m) {
    const float s = ps[(b * PN + j0 + m) * 4 + c];
    sv[m] = s;
    if (s > 0.5f) { flg |= 1 << m; ++cnt; }
    if (s > vmax) { vmax = s; jmax = j0 + m; }      // ascending: > = first
  }

  __shared__ float lv[256];
  __shared__ int   lj[256];
  __shared__ int   pre[256];
  lv[t] = vmax; lj[t] = jmax; pre[t] = cnt;
  __syncthreads();
  for (int off = 128; off > 0; off >>= 1) {         // argmax reduce
    if (t < off) {
      const float v2 = lv[t + off]; const int j2 = lj[t + off];
      if (v2 > lv[t] || (v2 == lv[t] && j2 < lj[t])) { lv[t] = v2; lj[t] = j2; }
    }
    __syncthreads();
  }
  for (int off = 1; off < 256; off <<= 1) {         // inclusive scan
    const int add = (t >= off) ? pre[t - off] : 0;
    __syncthreads();
    pre[t] += add;
    __syncthreads();
  }
  const int  totalTh = pre[255];
  const int  excl    = pre[t] - cnt;
  const int  jArg    = lj[0];
  const bool lab     = labels[b * 4 + c] != 0.0f;
  const int  L    = (!lab) ? 0 : ((totalTh > 1) ? totalTh : 1);
  const int  Lpad = (L + 7) & ~7;

  __shared__ float4 lastRoi;
  __shared__ float  lastS, lastA;
  float4* dstR = roiList + bc * CAP;
  float*  dstS = sList   + bc * CAP;
  float*  dstA = areaL   + bc * CAP;
  const float4* rb = ((const float4*)rois) + b * PN;

  if (lab) {
    if (totalTh > 1) {
      int pos = excl;
      #pragma unroll
      for (int m = 0; m < 8; ++m) {
        if (flg & (1 << m)) {
          const float4 r = rb[j0 + m];
          const float  a = (r.z - r.x) * (r.w - r.y);
          dstR[pos] = r; dstS[pos] = sv[m]; dstA[pos] = a;
          if (pos == L - 1) { lastRoi = r; lastS = sv[m]; lastA = a; }
          ++pos;
        }
      }
    } else if (t == (jArg >> 3)) {
      const float4 r = rb[jArg];
      const float  a = (r.z - r.x) * (r.w - r.y);
      dstR[0] = r; dstS[0] = sv[jArg & 7]; dstA[0] = a;
      lastRoi = r; lastS = sv[jArg & 7]; lastA = a;
    }
  }
  __syncthreads();
  if (t < Lpad - L) { dstR[L + t] = lastRoi; dstS[L + t] = lastS; dstA[L + t] = lastA; }
  if (t == 0) meta[bc] = Lpad;
}

// ---------------- K2: IoU rational-argmax partials (round-0 proven) ---------
__global__ __launch_bounds__(1024, 8) void k_assign(
    const float* __restrict__ rois, const int* __restrict__ meta,
    const float4* __restrict__ roiList, const float* __restrict__ areaL,
    float* __restrict__ pbn, float* __restrict__ pbd, int* __restrict__ pbp)
{
  const int blk   = blockIdx.x;
  const int h     = blk & 1;
  const int itile = (blk >> 1) & 31;
  const int b     = blk >> 6;
  const int t     = threadIdx.x;
  const int lane  = t & 63;
  const int wv    = t >> 6;

  __shared__ __align__(16) char ldsraw[61440];      // 60 KB
  float4* sroi  = (float4*)ldsraw;                  // [3][1024] 48 KB
  float*  sarea = (float*)(ldsraw + 49152);         // [3][1024] 12 KB
  float*  mn    = (float*)ldsraw;                   // merge aliases (post-barrier)
  float*  md    = (float*)(ldsraw + 12288);
  int*    mp    = (int*)(ldsraw + 24576);

  int startc[3], cntc[3];
  #pragma unroll
  for (int c = 0; c < 3; ++c) {
    const int L  = meta[b * 3 + c];                 // padded, mult of 8
    const int L2 = ((L >> 1) + 7) & ~7;             // h-split point
    const int s0 = h ? L2 : 0;
    const int e0 = h ? L  : L2;
    startc[c] = s0;
    cntc[c]   = e0 - s0;                            // <= 1024, mult of 8
    if (t < cntc[c]) {                              // one coalesced step
      sroi [c * 1024 + t] = roiList[(b * 3 + c) * CAP + s0 + t];
      sarea[c * 1024 + t] = areaL  [(b * 3 + c) * CAP + s0 + t];
    }
  }
  const int i = (itile << 6) + lane;
  const float4 ri = ((const float4*)rois)[b * PN + i];
  const float areai = (ri.z - ri.x) * (ri.w - ri.y);
  __syncthreads();

  float BN[3], BD[3]; int BP[3];
  #pragma unroll
  for (int c = 0; c < 3; ++c) {
    const int cnt = cntc[c];
    const int C   = (((cnt + 15) >> 4) + 7) & ~7;   // per-wave chunk, mult 8
    const int g0  = wv * C;
    int g1 = g0 + C; if (g1 > cnt) g1 = cnt;
    float nA = -2.0f, dA = 1.0f, nB = -2.0f, dB = 1.0f;
    int   pA = 0, pB = 0;
    const float4* rbase = sroi  + c * 1024;
    const float*  abase = sarea + c * 1024;

    auto upd = [&](float& n, float& d, int& p,
                   const float4 rj, const float aj, const int pos) {
      const float lx = fmaxf(ri.x, rj.x), ly = fmaxf(ri.y, rj.y);
      const float rx = fminf(ri.z, rj.z), ry = fminf(ri.w, rj.w);
      const float ww = fmaxf(rx - lx, 0.0f), hh = fmaxf(ry - ly, 0.0f);
      const float inter = ww * hh;
      const float uni   = areai + aj - inter;       // >= 1 always
      if (inter * d > n * uni) { n = inter; d = uni; p = pos; }
    };

    for (int g = g0; g < g1; g += 4) {
      const float4 r0 = rbase[g], r1 = rbase[g+1], r2 = rbase[g+2], r3 = rbase[g+3];
      const float  a0 = abase[g], a1 = abase[g+1], a2 = abase[g+2], a3 = abase[g+3];
      upd(nA, dA, pA, r0, a0, g);                   // chain A: g, g+1, ...
      upd(nB, dB, pB, r2, a2, g + 2);               // chain B: g+2, g+3, ...
      upd(nA, dA, pA, r1, a1, g + 1);
      upd(nB, dB, pB, r3, a3, g + 3);
    }
    // merge B into A with exact-tie -> lower position (ref = first max)
    const float tB = nB * dA, tA = nA * dB;
    if (tB > tA || (tB == tA && pB < pA)) { nA = nB; dA = dB; pA = pB; }
    BN[c] = nA; BD[c] = dA; BP[c] = pA + startc[c];
  }
  __syncthreads();                                  // stage reads done
  #pragma unroll
  for (int c = 0; c < 3; ++c) {
    mn[(c * NW + wv) * 64 + lane] = BN[c];
    md[(c * NW + wv) * 64 + lane] = BD[c];
    mp[(c * NW + wv) * 64 + lane] = BP[c];
  }
  __syncthreads();
  if (wv == 0) {
    #pragma unroll
    for (int c = 0; c < 3; ++c) {
      float bn = BN[c], bd = BD[c]; int bp = BP[c];
      for (int w2 = 1; w2 < NW; ++w2) {             // wv-ascending: > = first
        const float n = mn[(c * NW + w2) * 64 + lane];
        const float d = md[(c * NW + w2) * 64 + lane];
        const int   p = mp[(c * NW + w2) * 64 + lane];
        if (n * bd > bn * d) { bn = n; bd = d; bp = p; }
      }
      const int o = ((b * 3 + c) * 2 + h) * PN + i;
      pbn[o] = bn; pbd[o] = bd; pbp[o] = bp;
    }
  }
}

// ---------------- K3: merge halves + epilogue + loss (ticketed finalize) -----
__global__ __launch_bounds__(256) void k_back(
    const float* __restrict__ pbn, const float* __restrict__ pbd,
    const int* __restrict__ pbp, const float* __restrict__ sList,
    const float* __restrict__ logit, const float* __restrict__ labels,
    float* __restrict__ accum, float* __restrict__ loss)
{
  const int t  = threadIdx.x;
  const int gi = blockIdx.x * 256 + t;              // 0..16383
  const int b  = gi >> 11;
  const int i  = gi & (PN - 1);

  float v[3], sc[3];
  #pragma unroll
  for (int c = 0; c < 3; ++c) {
    const int o0 = ((b * 3 + c) * 2) * PN + i;
    float n = pbn[o0], d = pbd[o0]; int p = pbp[o0];
    const float n1 = pbn[o0 + PN], d1 = pbd[o0 + PN];
    const int   p1 = pbp[o0 + PN];
    if (n1 * d > n * d1) { n = n1; d = d1; p = p1; }  // h-ascending: > = first
    v[c]  = n / d;                                    // exact IEEE divide
    sc[c] = sList[(b * 3 + c) * CAP + p];
  }
  float runI = -1.0f, runw = 1.0f;
  if (v[0] > runI) { runw = sc[0]; runI = v[0]; }
  if (v[1] > runI) { runw = sc[1]; runI = v[1]; }
  if (v[2] > runI) { runw = sc[2]; runI = v[2]; }
  const float y0 = (v[0] > 0.5f) ? 1.0f : 0.0f;
  const float y1 = (v[1] > 0.5f) ? 1.0f : 0.0f;
  const float y2 = (v[2] > 0.5f) ? 1.0f : 0.0f;
  const float y3 = (y0 + y1 + y2 == 0.0f) ? 1.0f : 0.0f;

  const float4 lg = ((const float4*)logit)[gi];
  const float lb0 = labels[b * 4 + 0];
  const float lb1 = labels[b * 4 + 1];
  const float lb2 = labels[b * 4 + 2];

  auto term = [&](const float l, const float yv, const float labv) -> float {
    const float p  = fminf(fmaxf(l, 1e-7f), 1.0f - 1e-7f);
    const float om = 1.0f - p;
    const float fl = -yv * logf(p) * om * om;       // focal, gamma=2
    const float wl = 10.0f * expf(l) * (1.0f - labv) + labv;
    return runw * fl * wl;                          // /imb deferred
  };
  float s[8];
  s[0] = term(lg.x, y0, lb0); s[1] = term(lg.y, y1, lb1);
  s[2] = term(lg.z, y2, lb2); s[3] = term(lg.w, y3, 1.0f);
  s[4] = y0; s[5] = y1; s[6] = y2; s[7] = y3;

  #pragma unroll
  for (int k = 0; k < 8; ++k)
    #pragma unroll
    for (int off = 32; off; off >>= 1) s[k] += __shfl_xor(s[k], off);

  __shared__ float red[4][8];
  const int wv = t >> 6;
  if ((t & 63) == 0)
    #pragma unroll
    for (int k = 0; k < 8; ++k) red[wv][k] = s[k];
  __syncthreads();
  if (t < 8) {
    const float sum = red[0][t] + red[1][t] + red[2][t] + red[3][t];
    atomicAdd(&accum[t], sum);
  }
  __syncthreads();                                  // block's 8 adds drained
  if (t == 0) {
    __threadfence();
    const int ticket = __hip_atomic_fetch_add((int*)(accum + 8), 1,
                        __ATOMIC_ACQ_REL, __HIP_MEMORY_SCOPE_AGENT);
    if (ticket == 63) {                             // last block finalizes
      float L = 0.0f;
      #pragma unroll
      for (int c = 0; c < 4; ++c) {
        const float num = __hip_atomic_load(accum + c,
                            __ATOMIC_RELAXED, __HIP_MEMORY_SCOPE_AGENT);
        const float den = __hip_atomic_load(accum + 4 + c,
                            __ATOMIC_RELAXED, __HIP_MEMORY_SCOPE_AGENT);
        L += num / (den + 1e-7f);
      }
      loss[0] = L * 0.125f;                         // / bs, exact (pow2)
    }
  }
}

extern "C" void kernel_launch(void* const* d_in, const int* in_sizes, int n_in,
                              void* d_out, int out_size, void* d_ws, size_t ws_size,
                              hipStream_t stream)
{
  (void)in_sizes; (void)n_in; (void)out_size; (void)ws_size;
  const float* inp    = (const float*)d_in[0];
  const float* fcw    = (const float*)d_in[1];
  const float* fcb    = (const float*)d_in[2];
  const float* ps     = (const float*)d_in[3];
  const float* labels = (const float*)d_in[4];
  const float* rois   = (const float*)d_in[5];
  float* out = (float*)d_out;                       // 65536 logit + 1 loss

  char* ws = (char*)d_ws;
  float*  accum   = (float*) (ws);
  int*    meta    = (int*)   (ws + 64);
  float*  sList   = (float*) (ws + 1024);
  float*  areaL   = (float*) (ws + 197632);
  float4* roiL    = (float4*)(ws + 394240);
  float*  pbn     = (float*) (ws + 1180672);
  float*  pbd     = (float*) (ws + 1573888);
  int*    pbp     = (int*)   (ws + 1967104);

  k_front <<<1048, 256, 0, stream>>>(inp, fcw, fcb, ps, labels, rois,
                                     out, accum, meta, sList, areaL, roiL);
  k_assign<<<512, 1024, 0, stream>>>(rois, meta, roiL, areaL, pbn, pbd, pbp);
  k_back  <<<64,   256, 0, stream>>>(pbn, pbd, pbp, sList, out, labels, accum,
                                     out + BSZ * PN * 4);
}